// Round 1
// baseline (110.851 us; speedup 1.0000x reference)
//
#include <hip/hip_runtime.h>

// Problem constants (from reference): B=128, T=4096, N=16, D=3
#define BB 128
#define TT 4096
#define NN 16
#define DD 3
#define SLAB (NN*DD)          // 48 floats per (b,t)
#define TPB 256               // threads per block; T/TPB = 16 chunks

// Analytic inverse of the Jacobi-coordinate matrix A:
//   x0 = sum_j m_j r_j / M_tot        (center of mass)
//   x_i = r_i - COM(r_0..r_{i-1})     (i >= 1)
// Inverse (c_k = m_k / M_k, M_k = prefix sum):
//   r_k = x0 + x_k - sum_{i=k}^{N-1} c_i x_i   (k >= 1)
//   r_0 = x0 - sum_{i=1}^{N-1} c_i x_i
__global__ __launch_bounds__(TPB) void jacobi_to_cartesian_kernel(
    const float* __restrict__ m,
    const float* __restrict__ qj,
    const float* __restrict__ vj,
    float* __restrict__ outq,
    float* __restrict__ outv)
{
    __shared__ float cs[NN];

    const int b     = blockIdx.x >> 4;   // blockIdx.x / (T/TPB)
    const int chunk = blockIdx.x & 15;

    if (threadIdx.x == 0) {
        float M = 0.f;
        #pragma unroll
        for (int k = 0; k < NN; ++k) {
            float mk = m[b * NN + k];
            M += mk;
            cs[k] = mk / M;
        }
    }
    __syncthreads();

    const int t = chunk * TPB + threadIdx.x;
    const size_t off = ((size_t)b * TT + t) * SLAB;

    // blockIdx.y selects q (0) or v (1) — same transform, different buffers.
    const float4* __restrict__ src =
        (const float4*)((blockIdx.y ? vj : qj) + off);
    float4* __restrict__ dst =
        (float4*)((blockIdx.y ? outv : outq) + off);

    float x[SLAB];
    #pragma unroll
    for (int i = 0; i < SLAB / 4; ++i) {
        float4 v = src[i];
        x[4*i+0] = v.x; x[4*i+1] = v.y; x[4*i+2] = v.z; x[4*i+3] = v.w;
    }

    float out[SLAB];
    #pragma unroll
    for (int d = 0; d < DD; ++d) {
        const float x0 = x[d];
        float S = 0.f;
        #pragma unroll
        for (int k = NN - 1; k >= 1; --k) {
            S = fmaf(cs[k], x[k*DD + d], S);      // S_k = sum_{i=k}^{15} c_i x_i
            out[k*DD + d] = x0 + x[k*DD + d] - S; // r_k
        }
        out[d] = x0 - S;                          // r_0
    }

    #pragma unroll
    for (int i = 0; i < SLAB / 4; ++i) {
        float4 o;
        o.x = out[4*i+0]; o.y = out[4*i+1]; o.z = out[4*i+2]; o.w = out[4*i+3];
        dst[i] = o;
    }
}

extern "C" void kernel_launch(void* const* d_in, const int* in_sizes, int n_in,
                              void* d_out, int out_size, void* d_ws, size_t ws_size,
                              hipStream_t stream) {
    const float* m  = (const float*)d_in[0];
    const float* qj = (const float*)d_in[1];
    const float* vj = (const float*)d_in[2];

    float* outq = (float*)d_out;
    float* outv = outq + (size_t)BB * TT * NN * DD;

    dim3 grid(BB * (TT / TPB), 2);  // 2048 x 2 blocks
    dim3 block(TPB);
    jacobi_to_cartesian_kernel<<<grid, block, 0, stream>>>(m, qj, vj, outq, outv);
}

// Round 3
// 62.827 us; speedup vs baseline: 1.7644x; 1.7644x over previous
//
#include <hip/hip_runtime.h>

// Problem constants (from reference): B=128, T=4096, N=16, D=3
#define BB 128
#define TT 4096
#define NN 16
#define DD 3
#define SLAB  (NN*DD)     // 48 floats per (b,t) slab
#define SLAB4 (SLAB/4)    // 12 float4 per slab
#define PAD4  (SLAB4+1)   // 13 float4 LDS stride: 13%8=5 -> uniform bank groups
#define TPB   256         // threads per block; T/TPB = 16 chunks

typedef float f4 __attribute__((ext_vector_type(4)));  // native vector: ok for nontemporal builtins

// Analytic inverse of the Jacobi-coordinate matrix A (no linalg.inv):
//   c_k = m_k / M_k  (M_k = prefix sum of masses)
//   r_k = x0 + x_k - sum_{i=k}^{N-1} c_i x_i   (k >= 1)
//   r_0 = x0 - sum_{i=1}^{N-1} c_i x_i
__global__ __launch_bounds__(TPB) void jacobi_to_cartesian_kernel(
    const float* __restrict__ m,
    const float* __restrict__ qj,
    const float* __restrict__ vj,
    float* __restrict__ outq,
    float* __restrict__ outv)
{
    __shared__ f4 lds[TPB * PAD4];   // 256*13*16 = 53248 B
    __shared__ float cs[NN];

    const int b     = blockIdx.x >> 4;   // blockIdx.x / (T/TPB)
    const int chunk = blockIdx.x & 15;

    if (threadIdx.x == 0) {
        float M = 0.f;
        #pragma unroll
        for (int k = 0; k < NN; ++k) {
            float mk = m[b * NN + k];
            M += mk;
            cs[k] = mk / M;
        }
    }

    const size_t base4 = ((size_t)b * TT + (size_t)chunk * TPB) * SLAB4;
    const f4* __restrict__ src =
        (const f4*)(blockIdx.y ? vj : qj) + base4;
    f4* __restrict__ dst =
        (f4*)(blockIdx.y ? outv : outq) + base4;

    // Phase 1: fully-coalesced global -> LDS (lane i reads base + i*16B)
    #pragma unroll
    for (int j = 0; j < SLAB4; ++j) {
        const int f   = threadIdx.x + j * TPB;   // global float4 index in tile
        const int s   = f / SLAB4;               // slab within tile
        const int sub = f % SLAB4;               // float4 within slab
        lds[s * PAD4 + sub] = src[f];
    }
    __syncthreads();   // also publishes cs[]

    // Phase 2: per-thread slab compute from LDS (b128 reads, uniform banks)
    float x[SLAB];
    #pragma unroll
    for (int j = 0; j < SLAB4; ++j) {
        const f4 v = lds[threadIdx.x * PAD4 + j];
        x[4*j+0] = v.x; x[4*j+1] = v.y; x[4*j+2] = v.z; x[4*j+3] = v.w;
    }

    #pragma unroll
    for (int d = 0; d < DD; ++d) {
        const float x0 = x[d];
        float S = 0.f;
        #pragma unroll
        for (int k = NN - 1; k >= 1; --k) {
            S = fmaf(cs[k], x[k*DD + d], S);      // suffix sum of c_i x_i
            x[k*DD + d] = x0 + x[k*DD + d] - S;   // r_k (in place)
        }
        x[d] = x0 - S;                            // r_0
    }

    #pragma unroll
    for (int j = 0; j < SLAB4; ++j) {
        f4 o;
        o.x = x[4*j+0]; o.y = x[4*j+1]; o.z = x[4*j+2]; o.w = x[4*j+3];
        lds[threadIdx.x * PAD4 + j] = o;
    }
    __syncthreads();

    // Phase 3: fully-coalesced LDS -> global, nontemporal (outputs not reused)
    #pragma unroll
    for (int j = 0; j < SLAB4; ++j) {
        const int f   = threadIdx.x + j * TPB;
        const int s   = f / SLAB4;
        const int sub = f % SLAB4;
        __builtin_nontemporal_store(lds[s * PAD4 + sub], &dst[f]);
    }
}

extern "C" void kernel_launch(void* const* d_in, const int* in_sizes, int n_in,
                              void* d_out, int out_size, void* d_ws, size_t ws_size,
                              hipStream_t stream) {
    const float* m  = (const float*)d_in[0];
    const float* qj = (const float*)d_in[1];
    const float* vj = (const float*)d_in[2];

    float* outq = (float*)d_out;
    float* outv = outq + (size_t)BB * TT * NN * DD;

    dim3 grid(BB * (TT / TPB), 2);  // 2048 x 2 blocks
    dim3 block(TPB);
    jacobi_to_cartesian_kernel<<<grid, block, 0, stream>>>(m, qj, vj, outq, outv);
}

// Round 4
// 61.030 us; speedup vs baseline: 1.8163x; 1.0295x over previous
//
#include <hip/hip_runtime.h>

// Problem constants (from reference): B=128, T=4096, N=16, D=3
#define BB 128
#define TT 4096
#define NN 16
#define DD 3
#define TPB 256
#define GROUPS (TPB/NN)            // 16 slabs per block
#define NBLK ((BB*TT)/GROUPS)      // 32768 blocks

// 12-byte aggregate, 4-B aligned -> compiler emits global_load_dwordx3
struct f3 { float a, b, c; };

// Lane-parallel analytic inverse of the Jacobi matrix (no LDS, no barriers):
//   c_k = m_k / M_k (prefix sum of masses), c_0 := 1
//   r_k = x0 + x_k - sum_{i=k}^{N-1} c_i x_i      (uniform for all k with c_0=1)
// 16 lanes per slab (one k per lane, 3 d-components per lane).
// Suffix sum via width-16 __shfl_down scan; x0 via width-16 broadcast.
__global__ __launch_bounds__(TPB) void jacobi_to_cartesian_kernel(
    const float* __restrict__ m,
    const float* __restrict__ qj,
    const float* __restrict__ vj,
    float* __restrict__ outq,
    float* __restrict__ outv)
{
    const int t = threadIdx.x;
    const int l = t & (NN - 1);                       // k index within slab
    const size_t slab = (size_t)blockIdx.x * GROUPS + (t >> 4);
    const int b = (int)(slab >> 12);                  // slab / TT (TT=4096)

    // c_l = m_l / M_l via width-16 inclusive prefix scan (DPP row ops)
    const float mk = m[b * NN + l];
    float M = mk;
    #pragma unroll
    for (int d = 1; d < NN; d <<= 1) {
        float tmp = __shfl_up(M, d, NN);
        if (l >= d) M += tmp;
    }
    const float c = (l == 0) ? 1.0f : mk / M;

    const size_t base = slab * (size_t)(NN * DD) + (size_t)l * DD;

    #pragma unroll
    for (int which = 0; which < 2; ++which) {
        const float* __restrict__ src = (which ? vj : qj) + base;
        float*       __restrict__ dst = (which ? outv : outq) + base;

        const f3 xv = *(const f3*)src;                // dwordx3, 768B/wave contiguous

        // y_l = c_l * x_l ; suffix-scan within the 16-lane group
        float y0 = c * xv.a, y1 = c * xv.b, y2 = c * xv.c;
        #pragma unroll
        for (int d = 1; d < NN; d <<= 1) {
            float t0 = __shfl_down(y0, d, NN);
            float t1 = __shfl_down(y1, d, NN);
            float t2 = __shfl_down(y2, d, NN);
            if (l + d < NN) { y0 += t0; y1 += t1; y2 += t2; }
        }

        // x0 = Jacobi coordinate 0 (the COM) = group's lane-0 value
        const float x00 = __shfl(xv.a, 0, NN);
        const float x01 = __shfl(xv.b, 0, NN);
        const float x02 = __shfl(xv.c, 0, NN);

        __builtin_nontemporal_store(x00 + xv.a - y0, dst + 0);
        __builtin_nontemporal_store(x01 + xv.b - y1, dst + 1);
        __builtin_nontemporal_store(x02 + xv.c - y2, dst + 2);
    }
}

extern "C" void kernel_launch(void* const* d_in, const int* in_sizes, int n_in,
                              void* d_out, int out_size, void* d_ws, size_t ws_size,
                              hipStream_t stream) {
    const float* m  = (const float*)d_in[0];
    const float* qj = (const float*)d_in[1];
    const float* vj = (const float*)d_in[2];

    float* outq = (float*)d_out;
    float* outv = outq + (size_t)BB * TT * NN * DD;

    jacobi_to_cartesian_kernel<<<NBLK, TPB, 0, stream>>>(m, qj, vj, outq, outv);
}